// Round 6
// baseline (190.208 us; speedup 1.0000x reference)
//
#include <hip/hip_runtime.h>

typedef float f32x4 __attribute__((ext_vector_type(4)));

#define S0 4096
#define P0 64
#define S1 1024
#define P1 256
#define C  128
#define N_PTS (S0 * P0)

#define SEG_PER_BLK   4                      // 1 segment per wave
#define ASSIGN_BLOCKS (S0 / SEG_PER_BLK)     // 1024
#define TOTAL_BLOCKS  2048
#define NR            ((long)N_PTS * C / 4)  // 8388608 float4
#define NS            ((long)S1 * C / 4)     // 32768 float4
#define CPY_STRIDE    ((long)TOTAL_BLOCKS * 256)  // 524288 -> exactly 16 iters
#define UNROLL        8

// ---------------------------------------------------------------------------
// Fused kernel.
// Blocks 0..1023: wave-cooperative assignment (1 wave = 1 segment, coalesced
//   1-KB steps, intra-half shfl reduction, register-held candidate rows),
//   then LDS-aggregated scatter atomics; last assign block (done-counter)
//   finalizes the scatter-mean. All blocks then run the batched streaming
//   copy (8 nt-loads in flight, nt-stores, no L2 retention).
// Blocks 1024..2047: copy only.
// ---------------------------------------------------------------------------
__global__ __launch_bounds__(256) void fused_kernel(
    const float* __restrict__ sp_feat,   // [S1, C]
    const float* __restrict__ pts_feat,  // [S0, P0, C]
    const float* __restrict__ hilb,      // [N, 3]
    const int*   __restrict__ l01,       // [S0]
    const f32x4* __restrict__ raw,       // [N*C/4]
    float*  __restrict__ out_assign,     // [N] (as float)
    f32x4*  __restrict__ o_pf,           // [N*C/4]
    f32x4*  __restrict__ o_h1,           // [N*C/4]
    f32x4*  __restrict__ o_spf,          // [S1*C/4]
    float*  __restrict__ out_coord,      // [S1*3]
    float*  __restrict__ ws_sum,         // [S1*3]
    float*  __restrict__ ws_cnt,         // [S1]
    unsigned* __restrict__ ws_done)      // [1]
{
    __shared__ float lsum[4][3][3];   // [wave][cand][xyz]
    __shared__ float lcnt[4][3];
    __shared__ int   last_flag;

    const int tid  = threadIdx.x;
    const int blk  = blockIdx.x;
    const int w    = tid >> 6;
    const int lane = tid & 63;

    if (blk < ASSIGN_BLOCKS) {
        if (tid < 36) ((float*)lsum)[tid] = 0.0f;
        if (tid < 12) ((float*)lcnt)[tid] = 0.0f;
        __syncthreads();

        const int s  = blk * SEG_PER_BLK + w;
        const int sm = (s - 1 < 0) ? 0 : s - 1;
        const int sp = (s + 1 >= S0) ? S0 - 1 : s + 1;
        const int id0 = l01[sm], id1 = l01[s], id2 = l01[sp];

        const int h = lane >> 5;             // which row of the 2-row window
        const int q = (lane & 31) * 4;       // this lane's 4 channels

        const f32x4 c0 = *reinterpret_cast<const f32x4*>(sp_feat + (size_t)id0 * C + q);
        const f32x4 c1 = *reinterpret_cast<const f32x4*>(sp_feat + (size_t)id1 * C + q);
        const f32x4 c2 = *reinterpret_cast<const f32x4*>(sp_feat + (size_t)id2 * C + q);

        const float* segb = pts_feat + (size_t)s * P0 * C;

        #pragma unroll 4
        for (int k = 0; k < 32; ++k) {
            const int row = 2 * k + h;
            f32x4 v = __builtin_nontemporal_load(
                reinterpret_cast<const f32x4*>(segb + (size_t)row * C + q));
            float p0 = v.x * c0.x + v.y * c0.y + v.z * c0.z + v.w * c0.w;
            float p1 = v.x * c1.x + v.y * c1.y + v.z * c1.z + v.w * c1.w;
            float p2 = v.x * c2.x + v.y * c2.y + v.z * c2.z + v.w * c2.w;
            #pragma unroll
            for (int off = 1; off < 32; off <<= 1) {   // stays within each half
                p0 += __shfl_xor(p0, off);
                p1 += __shfl_xor(p1, off);
                p2 += __shfl_xor(p2, off);
            }
            if ((lane & 31) == 0) {
                int kb = 0; float best = p0;
                if (p1 > best) { best = p1; kb = 1; }
                if (p2 > best) { best = p2; kb = 2; }
                const int gpt = s * P0 + row;
                out_assign[gpt] = (float)(kb == 0 ? id0 : (kb == 1 ? id1 : id2));
                const float* hp = hilb + (size_t)gpt * 3;
                atomicAdd(&lsum[w][kb][0], hp[0]);
                atomicAdd(&lsum[w][kb][1], hp[1]);
                atomicAdd(&lsum[w][kb][2], hp[2]);
                atomicAdd(&lcnt[w][kb], 1.0f);
            }
        }
        __syncthreads();

        if (tid < 12) {
            const int ww = tid / 3, kb = tid % 3;
            if (lcnt[ww][kb] > 0.0f) {
                const int s2 = blk * SEG_PER_BLK + ww;
                int nb = s2 - 1 + kb;
                nb = nb < 0 ? 0 : (nb >= S0 ? S0 - 1 : nb);
                const int id = l01[nb];
                atomicAdd(&ws_cnt[id], lcnt[ww][kb]);
                atomicAdd(&ws_sum[(size_t)id * 3 + 0], lsum[ww][kb][0]);
                atomicAdd(&ws_sum[(size_t)id * 3 + 1], lsum[ww][kb][1]);
                atomicAdd(&ws_sum[(size_t)id * 3 + 2], lsum[ww][kb][2]);
            }
        }
        __syncthreads();   // drains the ws atomics

        // ---- last assign block finalizes the scatter-mean ----
        if (tid == 0) {
            __threadfence();
            last_flag = (atomicAdd(ws_done, 1u) == ASSIGN_BLOCKS - 1) ? 1 : 0;
        }
        __syncthreads();
        if (last_flag) {
            for (int i = tid; i < S1 * 3; i += 256) {
                float sv = atomicAdd(&ws_sum[i], 0.0f);          // device-coherent read
                float cv = atomicAdd(&ws_cnt[i / 3], 0.0f);
                out_coord[i] = sv / fmaxf(cv, 1.0f);
            }
        }
    }

    // ---- copy phase: batched streaming, all blocks ----
    const long gid = (long)blk * 256 + tid;
    if (gid < NS) o_spf[gid] = ((const f32x4*)sp_feat)[gid];

    // decorrelate the 2^27-aliased write pair per block
    f32x4* __restrict__ A = (blk & 1) ? o_h1 : o_pf;
    f32x4* __restrict__ B = (blk & 1) ? o_pf : o_h1;

    #pragma unroll
    for (int batch = 0; batch < 2; ++batch) {
        f32x4 v[UNROLL];
        #pragma unroll
        for (int t = 0; t < UNROLL; ++t)
            v[t] = __builtin_nontemporal_load(
                &raw[gid + (long)(batch * UNROLL + t) * CPY_STRIDE]);
        #pragma unroll
        for (int t = 0; t < UNROLL; ++t) {
            const long i = gid + (long)(batch * UNROLL + t) * CPY_STRIDE;
            __builtin_nontemporal_store(v[t], &A[i]);
            __builtin_nontemporal_store(v[t], &B[i]);
        }
    }
}

extern "C" void kernel_launch(void* const* d_in, const int* in_sizes, int n_in,
                              void* d_out, int out_size, void* d_ws, size_t ws_size,
                              hipStream_t stream) {
    const float* sp_feat  = (const float*)d_in[0];
    // d_in[1] sp_center_coord: unused (only affects tie-order among duplicates)
    const float* raw      = (const float*)d_in[2];
    const float* hilb     = (const float*)d_in[3];
    const float* pts_feat = (const float*)d_in[4];
    // d_in[5] points_coord: unused
    const int*   l01      = (const int*)d_in[6];

    float* out        = (float*)d_out;
    float* out_assign = out;                              // N
    float* out_spfeat = out_assign + N_PTS;               // S1*C
    float* out_coord  = out_spfeat + (size_t)S1 * C;      // S1*3
    float* out_pf     = out_coord + (size_t)S1 * 3;       // S0*P0*C
    float* out_h1     = out_pf + (size_t)S0 * P0 * C;     // S1*P1*C

    float*    ws_sum  = (float*)d_ws;                 // S1*3
    float*    ws_cnt  = ws_sum + (size_t)S1 * 3;      // S1
    unsigned* ws_done = (unsigned*)(ws_cnt + S1);     // 1

    (void)hipMemsetAsync(d_ws, 0, (size_t)(S1 * 3 + S1 + 1) * sizeof(float), stream);

    fused_kernel<<<TOTAL_BLOCKS, 256, 0, stream>>>(
        sp_feat, pts_feat, hilb, l01, (const f32x4*)raw,
        out_assign, (f32x4*)out_pf, (f32x4*)out_h1, (f32x4*)out_spfeat,
        out_coord, ws_sum, ws_cnt, ws_done);
}

// Round 7
// 158.478 us; speedup vs baseline: 1.2002x; 1.2002x over previous
//
#include <hip/hip_runtime.h>

typedef float f32x4 __attribute__((ext_vector_type(4)));

#define S0 4096
#define P0 64
#define S1 1024
#define P1 256
#define C  128
#define N_PTS (S0 * P0)

#define SEG_PER_BLK     4                      // 1 segment per wave
#define ASSIGN_BLOCKS   (S0 / SEG_PER_BLK)     // 1024, assign-only
#define COPY_BLOCKS     4096                   // short copy blocks (backfill)
#define TOTAL_BLOCKS    (ASSIGN_BLOCKS + COPY_BLOCKS)
#define NR              ((long)N_PTS * C / 4)  // 8388608 float4
#define NS              ((long)S1 * C / 4)     // 32768 float4
#define F4_PER_COPY_BLK (NR / COPY_BLOCKS)     // 2048 float4 = 32 KB source

// ---------------------------------------------------------------------------
// Blocks 0..1023: assignment only (1 wave = 1 segment, coalesced 1-KB steps,
//   intra-half shfl reduction, register-held candidate rows), LDS-aggregated
//   scatter atomics; the last assign block finalizes the scatter-mean.
// Blocks 1024..5119: copy only — each owns a contiguous 2048-float4 slice of
//   rawPoint_feat, 8 loads in flight, dual store. Short blocks retire fast
//   and the scheduler backfills around the long-latency assign blocks.
// ---------------------------------------------------------------------------
__global__ __launch_bounds__(256) void fused_kernel(
    const float* __restrict__ sp_feat,   // [S1, C]
    const float* __restrict__ pts_feat,  // [S0, P0, C]
    const float* __restrict__ hilb,      // [N, 3]
    const int*   __restrict__ l01,       // [S0]
    const f32x4* __restrict__ raw,       // [N*C/4]
    float*  __restrict__ out_assign,     // [N] (as float)
    f32x4*  __restrict__ o_pf,           // [N*C/4]
    f32x4*  __restrict__ o_h1,           // [N*C/4]
    f32x4*  __restrict__ o_spf,          // [S1*C/4]
    float*  __restrict__ out_coord,      // [S1*3]
    float*  __restrict__ ws_sum,         // [S1*3]
    float*  __restrict__ ws_cnt,         // [S1]
    unsigned* __restrict__ ws_done)      // [1]
{
    __shared__ float lsum[4][3][3];   // [wave][cand][xyz]
    __shared__ float lcnt[4][3];
    __shared__ int   last_flag;

    const int tid = threadIdx.x;
    const int blk = blockIdx.x;

    if (blk >= ASSIGN_BLOCKS) {
        // ---------------- copy-only path ----------------
        const int  cb   = blk - ASSIGN_BLOCKS;
        const long base = (long)cb * F4_PER_COPY_BLK;

        if (cb < 128) {                       // sp_center_feat passthrough
            const long g = (long)cb * 256 + tid;
            o_spf[g] = ((const f32x4*)sp_feat)[g];
        }

        f32x4 v[8];
        #pragma unroll
        for (int t = 0; t < 8; ++t)
            v[t] = raw[base + (long)t * 256 + tid];
        #pragma unroll
        for (int t = 0; t < 8; ++t) {
            const long i = base + (long)t * 256 + tid;
            o_pf[i] = v[t];
            o_h1[i] = v[t];
        }
        return;
    }

    // ---------------- assign path ----------------
    const int w    = tid >> 6;
    const int lane = tid & 63;

    if (tid < 36) ((float*)lsum)[tid] = 0.0f;
    if (tid < 12) ((float*)lcnt)[tid] = 0.0f;
    __syncthreads();

    const int s  = blk * SEG_PER_BLK + w;
    const int sm = (s - 1 < 0) ? 0 : s - 1;
    const int sp = (s + 1 >= S0) ? S0 - 1 : s + 1;
    const int id0 = l01[sm], id1 = l01[s], id2 = l01[sp];

    const int h = lane >> 5;             // which row of the 2-row window
    const int q = (lane & 31) * 4;       // this lane's 4 channels

    const f32x4 c0 = *reinterpret_cast<const f32x4*>(sp_feat + (size_t)id0 * C + q);
    const f32x4 c1 = *reinterpret_cast<const f32x4*>(sp_feat + (size_t)id1 * C + q);
    const f32x4 c2 = *reinterpret_cast<const f32x4*>(sp_feat + (size_t)id2 * C + q);

    const float* segb = pts_feat + (size_t)s * P0 * C;

    #pragma unroll 4
    for (int k = 0; k < 32; ++k) {
        const int row = 2 * k + h;
        f32x4 v = *reinterpret_cast<const f32x4*>(segb + (size_t)row * C + q);
        float p0 = v.x * c0.x + v.y * c0.y + v.z * c0.z + v.w * c0.w;
        float p1 = v.x * c1.x + v.y * c1.y + v.z * c1.z + v.w * c1.w;
        float p2 = v.x * c2.x + v.y * c2.y + v.z * c2.z + v.w * c2.w;
        #pragma unroll
        for (int off = 1; off < 32; off <<= 1) {   // stays within each half
            p0 += __shfl_xor(p0, off);
            p1 += __shfl_xor(p1, off);
            p2 += __shfl_xor(p2, off);
        }
        if ((lane & 31) == 0) {
            int kb = 0; float best = p0;
            if (p1 > best) { best = p1; kb = 1; }
            if (p2 > best) { best = p2; kb = 2; }
            const int gpt = s * P0 + row;
            out_assign[gpt] = (float)(kb == 0 ? id0 : (kb == 1 ? id1 : id2));
            const float* hp = hilb + (size_t)gpt * 3;
            atomicAdd(&lsum[w][kb][0], hp[0]);
            atomicAdd(&lsum[w][kb][1], hp[1]);
            atomicAdd(&lsum[w][kb][2], hp[2]);
            atomicAdd(&lcnt[w][kb], 1.0f);
        }
    }
    __syncthreads();

    if (tid < 12) {
        const int ww = tid / 3, kb = tid % 3;
        if (lcnt[ww][kb] > 0.0f) {
            const int s2 = blk * SEG_PER_BLK + ww;
            int nb = s2 - 1 + kb;
            nb = nb < 0 ? 0 : (nb >= S0 ? S0 - 1 : nb);
            const int id = l01[nb];
            atomicAdd(&ws_cnt[id], lcnt[ww][kb]);
            atomicAdd(&ws_sum[(size_t)id * 3 + 0], lsum[ww][kb][0]);
            atomicAdd(&ws_sum[(size_t)id * 3 + 1], lsum[ww][kb][1]);
            atomicAdd(&ws_sum[(size_t)id * 3 + 2], lsum[ww][kb][2]);
        }
    }
    __syncthreads();   // drains the ws atomics

    // ---- last assign block finalizes the scatter-mean ----
    if (tid == 0) {
        __threadfence();
        last_flag = (atomicAdd(ws_done, 1u) == ASSIGN_BLOCKS - 1) ? 1 : 0;
    }
    __syncthreads();
    if (last_flag) {
        for (int i = tid; i < S1 * 3; i += 256) {
            float sv = atomicAdd(&ws_sum[i], 0.0f);          // device-coherent read
            float cv = atomicAdd(&ws_cnt[i / 3], 0.0f);
            out_coord[i] = sv / fmaxf(cv, 1.0f);
        }
    }
}

extern "C" void kernel_launch(void* const* d_in, const int* in_sizes, int n_in,
                              void* d_out, int out_size, void* d_ws, size_t ws_size,
                              hipStream_t stream) {
    const float* sp_feat  = (const float*)d_in[0];
    // d_in[1] sp_center_coord: unused (only affects tie-order among duplicates)
    const float* raw      = (const float*)d_in[2];
    const float* hilb     = (const float*)d_in[3];
    const float* pts_feat = (const float*)d_in[4];
    // d_in[5] points_coord: unused
    const int*   l01      = (const int*)d_in[6];

    float* out        = (float*)d_out;
    float* out_assign = out;                              // N
    float* out_spfeat = out_assign + N_PTS;               // S1*C
    float* out_coord  = out_spfeat + (size_t)S1 * C;      // S1*3
    float* out_pf     = out_coord + (size_t)S1 * 3;       // S0*P0*C
    float* out_h1     = out_pf + (size_t)S0 * P0 * C;     // S1*P1*C

    float*    ws_sum  = (float*)d_ws;                 // S1*3
    float*    ws_cnt  = ws_sum + (size_t)S1 * 3;      // S1
    unsigned* ws_done = (unsigned*)(ws_cnt + S1);     // 1

    (void)hipMemsetAsync(d_ws, 0, (size_t)(S1 * 3 + S1 + 1) * sizeof(float), stream);

    fused_kernel<<<TOTAL_BLOCKS, 256, 0, stream>>>(
        sp_feat, pts_feat, hilb, l01, (const f32x4*)raw,
        out_assign, (f32x4*)out_pf, (f32x4*)out_h1, (f32x4*)out_spfeat,
        out_coord, ws_sum, ws_cnt, ws_done);
}